// Round 1
// baseline (1139.436 us; speedup 1.0000x reference)
//
#include <hip/hip_runtime.h>

#define EDGES   800000
#define IN_F    64
#define HID     128
#define TPB     512                 // 8 waves per WG
#define EPW     32                  // edges per wave = one 32-col MFMA tile
#define EPB     256                 // edges per WG (8 waves * 32)
#define NBLK    (EDGES / EPB)       // 3125 edge blocks
#define GRID    512                 // persistent: exactly 2 WG/CU (80 KiB LDS each)

// LDS weight cache layout: [w1 16KB | w2 32KB | w3 32KB], f16, XOR-swizzled.
#define W1_OFF  0
#define W2_OFF  16384
#define W3_OFF  49152
#define LDSB    81920

typedef _Float16 half8  __attribute__((ext_vector_type(8)));
typedef __fp16   fp16x2 __attribute__((ext_vector_type(2)));
typedef float    f32x16 __attribute__((ext_vector_type(16)));
typedef unsigned u32;
typedef u32      u32x2  __attribute__((ext_vector_type(2)));
typedef u32      u32x4  __attribute__((ext_vector_type(4)));

union H8U { u32x4 u; half8 h; };

__device__ __forceinline__ float fast_tanh(float x) {
    // tanh(x) = 1 - 2/(e^{2x}+1); preacts bounded, no overflow.
    float e = __builtin_amdgcn_exp2f(2.8853900817779268f * x);
    return 1.0f - 2.0f * __builtin_amdgcn_rcpf(e + 1.0f);
}
__device__ __forceinline__ float fast_sigmoid(float x) {
    return __builtin_amdgcn_rcpf(1.0f + __builtin_amdgcn_exp2f(-1.4426950408889634f * x));
}
__device__ __forceinline__ u32 pk2(float a, float b) {
    fp16x2 p = __builtin_amdgcn_cvt_pkrtz(a, b);
    return __builtin_bit_cast(u32, p);
}

// One 32x32 output tile: D = W[32it..32it+31][:] x Act (B-frags), bias-init.
//   A-frag: lane holds W[row = 32it + (l&31)][k = s*16 + (l>>5)*8 + j]  (ds_read_b128, swizzled)
//   B-frag: lane holds Act[k = s*16 + (l>>5)*8 + j][e = l&31]
//   D:      lane holds O[h' = 32it + (reg&3) + 8*(reg>>2) + 4*(l>>5)][e = l&31]
template<int ROWSHIFT, int NS>
__device__ __forceinline__ f32x16 tile_mm(const char* LWbase, const u32* sw,
                                          int it, int col, int hi,
                                          const half8* fin, const float* bias) {
    f32x16 acc;
    #pragma unroll
    for (int M = 0; M < 4; ++M) {
        float4 bv = *(const float4*)(bias + it * 32 + M * 8 + hi * 4);
        acc[4*M+0] = bv.x; acc[4*M+1] = bv.y; acc[4*M+2] = bv.z; acc[4*M+3] = bv.w;
    }
    const int rowb = (it * 32 + col) << ROWSHIFT;
    #pragma unroll
    for (int s = 0; s < NS; ++s) {
        half8 afr = *(const half8*)(LWbase + rowb + (int)sw[s]);
        acc = __builtin_amdgcn_mfma_f32_32x32x16_f16(afr, fin[s], acc, 0, 0, 0);
    }
    return acc;
}

// tanh + pack 16 accs -> 8 dwords d[M][k] (rows 8M+4hi+{2k,2k+1}), then
// permlane32_swap pairs (d[2s][k], d[2s+1][k]) -> next layer B-frags:
//   frag[2it+s] = [r_k0[0], r_k1[0], r_k0[1], r_k1[1]]  (k fields w0..w3)
__device__ __forceinline__ void pack_swap(const f32x16& acc, half8& f_lo, half8& f_hi) {
    u32 d00 = pk2(fast_tanh(acc[0]),  fast_tanh(acc[1]));
    u32 d01 = pk2(fast_tanh(acc[2]),  fast_tanh(acc[3]));
    u32 d10 = pk2(fast_tanh(acc[4]),  fast_tanh(acc[5]));
    u32 d11 = pk2(fast_tanh(acc[6]),  fast_tanh(acc[7]));
    u32 d20 = pk2(fast_tanh(acc[8]),  fast_tanh(acc[9]));
    u32 d21 = pk2(fast_tanh(acc[10]), fast_tanh(acc[11]));
    u32 d30 = pk2(fast_tanh(acc[12]), fast_tanh(acc[13]));
    u32 d31 = pk2(fast_tanh(acc[14]), fast_tanh(acc[15]));
    u32x2 r0 = __builtin_amdgcn_permlane32_swap(d00, d10, false, false);
    u32x2 r1 = __builtin_amdgcn_permlane32_swap(d01, d11, false, false);
    u32x2 r2 = __builtin_amdgcn_permlane32_swap(d20, d30, false, false);
    u32x2 r3 = __builtin_amdgcn_permlane32_swap(d21, d31, false, false);
    H8U lo, hi;
    lo.u = (u32x4){r0[0], r1[0], r0[1], r1[1]};
    hi.u = (u32x4){r2[0], r3[0], r2[1], r3[1]};
    f_lo = lo.h;
    f_hi = hi.h;
}

__global__ __launch_bounds__(TPB, 4)
void gnn_mlp(const float* __restrict__ ea,
             const float* __restrict__ W1, const float* __restrict__ b1,
             const float* __restrict__ W2, const float* __restrict__ b2,
             const float* __restrict__ W3, const float* __restrict__ b3,
             const float* __restrict__ W4, const float* __restrict__ b4,
             float* __restrict__ out) {
    __shared__ __align__(16) char LW[LDSB];

    const int tid  = threadIdx.x;
    const int lane = tid & 63;
    const int wv   = tid >> 6;          // wave 0..7
    const int col  = lane & 31;         // edge column of the 32x32 tile
    const int hi   = lane >> 5;         // k-half selector

    // ---- stage weights: f32 -> f16, XOR-swizzled, once per WG ----
    // swizzle: phys = off ^ ((row & 7) << 4)  for 128B rows (w1)
    //          phys = off ^ ((row & 15) << 4) for 256B rows (w2/w3)
    // -> ds_read_b128 of a 32-row column slice lands 2-way per bank (free).
    #pragma unroll
    for (int i = 0; i < 10; ++i) {
        const int g   = i * TPB + tid;  // 16B granule id, 5120 total
        const int off = g << 4;
        const float* src; int phys;
        if (i < 2) {                    // w1: rows of 128 B
            int row = off >> 7;
            phys = W1_OFF + (off ^ ((row & 7) << 4));
            src  = W1 + (off >> 1);
        } else if (i < 6) {             // w2: rows of 256 B
            int rel = off - W2_OFF, row = rel >> 8;
            phys = W2_OFF + (rel ^ ((row & 15) << 4));
            src  = W2 + (rel >> 1);
        } else {                        // w3
            int rel = off - W3_OFF, row = rel >> 8;
            phys = W3_OFF + (rel ^ ((row & 15) << 4));
            src  = W3 + (rel >> 1);
        }
        float4 a = *(const float4*)(src);
        float4 b = *(const float4*)(src + 4);
        half8 h;
        h[0]=(_Float16)a.x; h[1]=(_Float16)a.y; h[2]=(_Float16)a.z; h[3]=(_Float16)a.w;
        h[4]=(_Float16)b.x; h[5]=(_Float16)b.y; h[6]=(_Float16)b.z; h[7]=(_Float16)b.w;
        *(half8*)(LW + phys) = h;
    }
    __syncthreads();   // only barrier in the kernel

    // per-lane swizzled in-row offsets, reused for every tile/layer
    u32 sw2[8], sw1[4];
    #pragma unroll
    for (int s = 0; s < 8; ++s) sw2[s] = (u32)(((s << 5) + (hi << 4)) ^ ((col & 15) << 4));
    #pragma unroll
    for (int s = 0; s < 4; ++s) sw1[s] = (u32)(((s << 5) + (hi << 4)) ^ ((col & 7) << 4));

    const float bb = b4[0];

    for (int blk = blockIdx.x; blk < NBLK; blk += GRID) {
        const long ebase = (long)blk * EPB + wv * EPW;

        // ---- layer-1 B-frags straight from global (f32 -> f16 RNE) ----
        const float* ep = ea + (ebase + col) * IN_F + hi * 8;
        half8 f1[4];
        #pragma unroll
        for (int s = 0; s < 4; ++s) {
            float4 a = *(const float4*)(ep + s * 16);
            float4 b = *(const float4*)(ep + s * 16 + 4);
            half8 h;
            h[0]=(_Float16)a.x; h[1]=(_Float16)a.y; h[2]=(_Float16)a.z; h[3]=(_Float16)a.w;
            h[4]=(_Float16)b.x; h[5]=(_Float16)b.y; h[6]=(_Float16)b.z; h[7]=(_Float16)b.w;
            f1[s] = h;
        }

        // ---- layer 1: 64 -> 128 ----
        half8 f2[8];
        #pragma unroll
        for (int it = 0; it < 4; ++it) {
            f32x16 acc = tile_mm<7, 4>(LW + W1_OFF, sw1, it, col, hi, f1, b1);
            pack_swap(acc, f2[2 * it], f2[2 * it + 1]);
        }

        // ---- layer 2: 128 -> 128 ----
        half8 f3[8];
        #pragma unroll
        for (int it = 0; it < 4; ++it) {
            f32x16 acc = tile_mm<8, 8>(LW + W2_OFF, sw2, it, col, hi, f2, b2);
            pack_swap(acc, f3[2 * it], f3[2 * it + 1]);
        }

        // ---- layer 3 + fused layer-4 dot ----
        float p = 0.0f;
        #pragma unroll
        for (int it = 0; it < 4; ++it) {
            f32x16 acc = tile_mm<8, 8>(LW + W3_OFF, sw2, it, col, hi, f3, b3);
            #pragma unroll
            for (int M = 0; M < 4; ++M) {
                float4 wv4 = *(const float4*)(W4 + it * 32 + M * 8 + hi * 4);
                p += fast_tanh(acc[4*M+0]) * wv4.x + fast_tanh(acc[4*M+1]) * wv4.y
                   + fast_tanh(acc[4*M+2]) * wv4.z + fast_tanh(acc[4*M+3]) * wv4.w;
            }
        }
        // full h-sum for edge `col` lives in lanes col and col+32
        p += __shfl_xor(p, 32, 64);
        if (lane < 32) out[ebase + col] = fast_sigmoid(p + bb);
    }
}

extern "C" void kernel_launch(void* const* d_in, const int* in_sizes, int n_in,
                              void* d_out, int out_size, void* d_ws, size_t ws_size,
                              hipStream_t stream) {
    // setup_inputs order: x, edge_index, edge_attr, W1,b1, W2,b2, W3,b3, W4,b4
    const float* ea = (const float*)d_in[2];
    const float* W1 = (const float*)d_in[3];
    const float* b1 = (const float*)d_in[4];
    const float* W2 = (const float*)d_in[5];
    const float* b2 = (const float*)d_in[6];
    const float* W3 = (const float*)d_in[7];
    const float* b3 = (const float*)d_in[8];
    const float* W4 = (const float*)d_in[9];
    const float* b4 = (const float*)d_in[10];
    float* out = (float*)d_out;

    hipLaunchKernelGGL(gnn_mlp, dim3(GRID), dim3(TPB), 0, stream,
                       ea, W1, b1, W2, b2, W3, b3, W4, b4, out);
}

// Round 2
// 962.407 us; speedup vs baseline: 1.1839x; 1.1839x over previous
//
#include <hip/hip_runtime.h>

#define EDGES   800000
#define IN_F    64
#define HID     128
#define TPB     512                 // 8 waves per WG
#define EPW     32                  // edges per wave = one 32-col MFMA tile
#define EPB     256                 // edges per WG (8 waves * 32)
#define NBLK    (EDGES / EPB)       // 3125 edge blocks
#define GRID    512                 // persistent: exactly 2 WG/CU (80 KiB LDS each)

// LDS weight cache layout: [w1 16KB | w2 32KB | w3 32KB], f16, XOR-swizzled.
#define W1_OFF  0
#define W2_OFF  16384
#define W3_OFF  49152
#define LDSB    81920

typedef _Float16 half8  __attribute__((ext_vector_type(8)));
typedef __fp16   fp16x2 __attribute__((ext_vector_type(2)));
typedef float    f32x16 __attribute__((ext_vector_type(16)));
typedef unsigned u32;
typedef u32      u32x2  __attribute__((ext_vector_type(2)));
typedef u32      u32x4  __attribute__((ext_vector_type(4)));

union H8U { u32x4 u; half8 h; };

__device__ __forceinline__ float fast_tanh(float x) {
    // tanh(x) = 1 - 2/(e^{2x}+1); preacts bounded, no overflow.
    float e = __builtin_amdgcn_exp2f(2.8853900817779268f * x);
    return 1.0f - 2.0f * __builtin_amdgcn_rcpf(e + 1.0f);
}
__device__ __forceinline__ float fast_sigmoid(float x) {
    return __builtin_amdgcn_rcpf(1.0f + __builtin_amdgcn_exp2f(-1.4426950408889634f * x));
}
__device__ __forceinline__ u32 pk2(float a, float b) {
    fp16x2 p = __builtin_amdgcn_cvt_pkrtz(a, b);
    return __builtin_bit_cast(u32, p);
}

// One 32x32 output tile: D = W[32it..32it+31][:] x Act (B-frags), bias-init.
//   A-frag: lane holds W[row = 32it + (l&31)][k = s*16 + (l>>5)*8 + j]  (ds_read_b128, swizzled)
//   B-frag: lane holds Act[k = s*16 + (l>>5)*8 + j][e = l&31]
//   D:      lane holds O[h' = 32it + (reg&3) + 8*(reg>>2) + 4*(l>>5)][e = l&31]
template<int ROWSHIFT, int NS>
__device__ __forceinline__ f32x16 tile_mm(const char* LWbase, const u32* sw,
                                          int it, int col, int hi,
                                          const half8* fin, const float* bias) {
    f32x16 acc;
    #pragma unroll
    for (int M = 0; M < 4; ++M) {
        float4 bv = *(const float4*)(bias + it * 32 + M * 8 + hi * 4);
        acc[4*M+0] = bv.x; acc[4*M+1] = bv.y; acc[4*M+2] = bv.z; acc[4*M+3] = bv.w;
    }
    const int rowb = (it * 32 + col) << ROWSHIFT;
    #pragma unroll
    for (int s = 0; s < NS; ++s) {
        half8 afr = *(const half8*)(LWbase + rowb + (int)sw[s]);
        acc = __builtin_amdgcn_mfma_f32_32x32x16_f16(afr, fin[s], acc, 0, 0, 0);
    }
    return acc;
}

// tanh + pack 16 accs -> 8 dwords d[M][k] (rows 8M+4hi+{2k,2k+1}), then
// permlane32_swap pairs (d[2s][k], d[2s+1][k]) -> next layer B-frags:
//   frag[2it+s] = [r_k0[0], r_k1[0], r_k0[1], r_k1[1]]  (k fields w0..w3)
__device__ __forceinline__ void pack_swap(const f32x16& acc, half8& f_lo, half8& f_hi) {
    u32 d00 = pk2(fast_tanh(acc[0]),  fast_tanh(acc[1]));
    u32 d01 = pk2(fast_tanh(acc[2]),  fast_tanh(acc[3]));
    u32 d10 = pk2(fast_tanh(acc[4]),  fast_tanh(acc[5]));
    u32 d11 = pk2(fast_tanh(acc[6]),  fast_tanh(acc[7]));
    u32 d20 = pk2(fast_tanh(acc[8]),  fast_tanh(acc[9]));
    u32 d21 = pk2(fast_tanh(acc[10]), fast_tanh(acc[11]));
    u32 d30 = pk2(fast_tanh(acc[12]), fast_tanh(acc[13]));
    u32 d31 = pk2(fast_tanh(acc[14]), fast_tanh(acc[15]));
    u32x2 r0 = __builtin_amdgcn_permlane32_swap(d00, d10, false, false);
    u32x2 r1 = __builtin_amdgcn_permlane32_swap(d01, d11, false, false);
    u32x2 r2 = __builtin_amdgcn_permlane32_swap(d20, d30, false, false);
    u32x2 r3 = __builtin_amdgcn_permlane32_swap(d21, d31, false, false);
    H8U lo, hi;
    lo.u = (u32x4){r0[0], r1[0], r0[1], r1[1]};
    hi.u = (u32x4){r2[0], r3[0], r2[1], r3[1]};
    f_lo = lo.h;
    f_hi = hi.h;
}

// launch_bounds note: (TPB, 4) made the allocator target 8 waves/SIMD ->
// 64-VGPR cap -> ~60 regs/thread spilled to scratch (561 MB WRITE_SIZE,
// 1.8 GB FETCH observed). LDS (80 KiB) already caps us at 2 WG/CU =
// 4 waves/SIMD, so ask only for that: cap >= 128 VGPR, no spills.
__global__ __launch_bounds__(TPB, 2)
void gnn_mlp(const float* __restrict__ ea,
             const float* __restrict__ W1, const float* __restrict__ b1,
             const float* __restrict__ W2, const float* __restrict__ b2,
             const float* __restrict__ W3, const float* __restrict__ b3,
             const float* __restrict__ W4, const float* __restrict__ b4,
             float* __restrict__ out) {
    __shared__ __align__(16) char LW[LDSB];

    const int tid  = threadIdx.x;
    const int lane = tid & 63;
    const int wv   = tid >> 6;          // wave 0..7
    const int col  = lane & 31;         // edge column of the 32x32 tile
    const int hi   = lane >> 5;         // k-half selector

    // ---- stage weights: f32 -> f16, XOR-swizzled, once per WG ----
    // swizzle: phys = off ^ ((row & 7) << 4)  for 128B rows (w1)
    //          phys = off ^ ((row & 15) << 4) for 256B rows (w2/w3)
    // -> ds_read_b128 of a 32-row column slice lands 2-way per bank (free).
    #pragma unroll
    for (int i = 0; i < 10; ++i) {
        const int g   = i * TPB + tid;  // 16B granule id, 5120 total
        const int off = g << 4;
        const float* src; int phys;
        if (i < 2) {                    // w1: rows of 128 B
            int row = off >> 7;
            phys = W1_OFF + (off ^ ((row & 7) << 4));
            src  = W1 + (off >> 1);
        } else if (i < 6) {             // w2: rows of 256 B
            int rel = off - W2_OFF, row = rel >> 8;
            phys = W2_OFF + (rel ^ ((row & 15) << 4));
            src  = W2 + (rel >> 1);
        } else {                        // w3
            int rel = off - W3_OFF, row = rel >> 8;
            phys = W3_OFF + (rel ^ ((row & 15) << 4));
            src  = W3 + (rel >> 1);
        }
        float4 a = *(const float4*)(src);
        float4 b = *(const float4*)(src + 4);
        half8 h;
        h[0]=(_Float16)a.x; h[1]=(_Float16)a.y; h[2]=(_Float16)a.z; h[3]=(_Float16)a.w;
        h[4]=(_Float16)b.x; h[5]=(_Float16)b.y; h[6]=(_Float16)b.z; h[7]=(_Float16)b.w;
        *(half8*)(LW + phys) = h;
    }
    __syncthreads();   // only barrier in the kernel

    // per-lane swizzled in-row offsets, reused for every tile/layer
    u32 sw2[8], sw1[4];
    #pragma unroll
    for (int s = 0; s < 8; ++s) sw2[s] = (u32)(((s << 5) + (hi << 4)) ^ ((col & 15) << 4));
    #pragma unroll
    for (int s = 0; s < 4; ++s) sw1[s] = (u32)(((s << 5) + (hi << 4)) ^ ((col & 7) << 4));

    const float bb = b4[0];

    for (int blk = blockIdx.x; blk < NBLK; blk += GRID) {
        const long ebase = (long)blk * EPB + wv * EPW;

        // ---- layer-1 B-frags straight from global (f32 -> f16 RNE) ----
        const float* ep = ea + (ebase + col) * IN_F + hi * 8;
        half8 f1[4];
        #pragma unroll
        for (int s = 0; s < 4; ++s) {
            float4 a = *(const float4*)(ep + s * 16);
            float4 b = *(const float4*)(ep + s * 16 + 4);
            half8 h;
            h[0]=(_Float16)a.x; h[1]=(_Float16)a.y; h[2]=(_Float16)a.z; h[3]=(_Float16)a.w;
            h[4]=(_Float16)b.x; h[5]=(_Float16)b.y; h[6]=(_Float16)b.z; h[7]=(_Float16)b.w;
            f1[s] = h;
        }

        // ---- layer 1: 64 -> 128 ----
        half8 f2[8];
        #pragma unroll
        for (int it = 0; it < 4; ++it) {
            f32x16 acc = tile_mm<7, 4>(LW + W1_OFF, sw1, it, col, hi, f1, b1);
            pack_swap(acc, f2[2 * it], f2[2 * it + 1]);
        }

        // ---- layer 2: 128 -> 128 ----
        half8 f3[8];
        #pragma unroll
        for (int it = 0; it < 4; ++it) {
            f32x16 acc = tile_mm<8, 8>(LW + W2_OFF, sw2, it, col, hi, f2, b2);
            pack_swap(acc, f3[2 * it], f3[2 * it + 1]);
        }

        // ---- layer 3 + fused layer-4 dot ----
        float p = 0.0f;
        #pragma unroll
        for (int it = 0; it < 4; ++it) {
            f32x16 acc = tile_mm<8, 8>(LW + W3_OFF, sw2, it, col, hi, f3, b3);
            #pragma unroll
            for (int M = 0; M < 4; ++M) {
                float4 wv4 = *(const float4*)(W4 + it * 32 + M * 8 + hi * 4);
                p += fast_tanh(acc[4*M+0]) * wv4.x + fast_tanh(acc[4*M+1]) * wv4.y
                   + fast_tanh(acc[4*M+2]) * wv4.z + fast_tanh(acc[4*M+3]) * wv4.w;
            }
        }
        // full h-sum for edge `col` lives in lanes col and col+32
        p += __shfl_xor(p, 32, 64);
        if (lane < 32) out[ebase + col] = fast_sigmoid(p + bb);
    }
}

extern "C" void kernel_launch(void* const* d_in, const int* in_sizes, int n_in,
                              void* d_out, int out_size, void* d_ws, size_t ws_size,
                              hipStream_t stream) {
    // setup_inputs order: x, edge_index, edge_attr, W1,b1, W2,b2, W3,b3, W4,b4
    const float* ea = (const float*)d_in[2];
    const float* W1 = (const float*)d_in[3];
    const float* b1 = (const float*)d_in[4];
    const float* W2 = (const float*)d_in[5];
    const float* b2 = (const float*)d_in[6];
    const float* W3 = (const float*)d_in[7];
    const float* b3 = (const float*)d_in[8];
    const float* W4 = (const float*)d_in[9];
    const float* b4 = (const float*)d_in[10];
    float* out = (float*)d_out;

    hipLaunchKernelGGL(gnn_mlp, dim3(GRID), dim3(TPB), 0, stream,
                       ea, W1, b1, W2, b2, W3, b3, W4, b4, out);
}

// Round 3
// 866.664 us; speedup vs baseline: 1.3147x; 1.1105x over previous
//
#include <hip/hip_runtime.h>

#define EDGES   800000
#define IN_F    64
#define HID     128
#define TPB     512                 // 8 waves per WG
#define EPW     32                  // edges per wave = one 32-col MFMA tile
#define EPB     256                 // edges per WG (8 waves * 32)
#define NBLK    (EDGES / EPB)       // 3125 edge blocks
#define GRID    256                 // persistent: 1 WG/CU (80 KiB LDS, ~180 VGPR)

// LDS weight cache layout: [w1 16KB | w2 32KB | w3 32KB], f16, XOR-swizzled.
#define W1_OFF  0
#define W2_OFF  16384
#define W3_OFF  49152
#define LDSB    81920

typedef _Float16 half8  __attribute__((ext_vector_type(8)));
typedef __fp16   fp16x2 __attribute__((ext_vector_type(2)));
typedef float    f32x16 __attribute__((ext_vector_type(16)));
typedef unsigned u32;
typedef u32      u32x2  __attribute__((ext_vector_type(2)));
typedef u32      u32x4  __attribute__((ext_vector_type(4)));

union H8U { u32x4 u; half8 h; };

__device__ __forceinline__ float fast_tanh(float x) {
    // tanh(x) = 1 - 2/(e^{2x}+1); preacts bounded, no overflow.
    float e = __builtin_amdgcn_exp2f(2.8853900817779268f * x);
    return 1.0f - 2.0f * __builtin_amdgcn_rcpf(e + 1.0f);
}
__device__ __forceinline__ float fast_sigmoid(float x) {
    return __builtin_amdgcn_rcpf(1.0f + __builtin_amdgcn_exp2f(-1.4426950408889634f * x));
}
__device__ __forceinline__ u32 pk2(float a, float b) {
    fp16x2 p = __builtin_amdgcn_cvt_pkrtz(a, b);
    return __builtin_bit_cast(u32, p);
}

// One 32x32 output tile: D = W[32it..32it+31][:] x Act (B-frags), bias-init.
//   A-frag: lane holds W[row = 32it + (l&31)][k = s*16 + (l>>5)*8 + j]  (ds_read_b128, swizzled)
//   B-frag: lane holds Act[k = s*16 + (l>>5)*8 + j][e = l&31]
//   D:      lane holds O[h' = 32it + (reg&3) + 8*(reg>>2) + 4*(l>>5)][e = l&31]
template<int ROWSHIFT, int NS>
__device__ __forceinline__ f32x16 tile_mm(const char* LWbase, const u32* sw,
                                          int it, int col, int hi,
                                          const half8* fin, const float* bias) {
    f32x16 acc;
    #pragma unroll
    for (int M = 0; M < 4; ++M) {
        float4 bv = *(const float4*)(bias + it * 32 + M * 8 + hi * 4);
        acc[4*M+0] = bv.x; acc[4*M+1] = bv.y; acc[4*M+2] = bv.z; acc[4*M+3] = bv.w;
    }
    const int rowb = (it * 32 + col) << ROWSHIFT;
    #pragma unroll
    for (int s = 0; s < NS; ++s) {
        half8 afr = *(const half8*)(LWbase + rowb + (int)sw[s]);
        acc = __builtin_amdgcn_mfma_f32_32x32x16_f16(afr, fin[s], acc, 0, 0, 0);
    }
    return acc;
}

// tanh + pack 16 accs -> 8 dwords d[M][k] (rows 8M+4hi+{2k,2k+1}), then
// permlane32_swap pairs (d[2s][k], d[2s+1][k]) -> next layer B-frags:
//   frag[2it+s] = [r_k0[0], r_k1[0], r_k0[1], r_k1[1]]  (k fields w0..w3)
__device__ __forceinline__ void pack_swap(const f32x16& acc, half8& f_lo, half8& f_hi) {
    u32 d00 = pk2(fast_tanh(acc[0]),  fast_tanh(acc[1]));
    u32 d01 = pk2(fast_tanh(acc[2]),  fast_tanh(acc[3]));
    u32 d10 = pk2(fast_tanh(acc[4]),  fast_tanh(acc[5]));
    u32 d11 = pk2(fast_tanh(acc[6]),  fast_tanh(acc[7]));
    u32 d20 = pk2(fast_tanh(acc[8]),  fast_tanh(acc[9]));
    u32 d21 = pk2(fast_tanh(acc[10]), fast_tanh(acc[11]));
    u32 d30 = pk2(fast_tanh(acc[12]), fast_tanh(acc[13]));
    u32 d31 = pk2(fast_tanh(acc[14]), fast_tanh(acc[15]));
    u32x2 r0 = __builtin_amdgcn_permlane32_swap(d00, d10, false, false);
    u32x2 r1 = __builtin_amdgcn_permlane32_swap(d01, d11, false, false);
    u32x2 r2 = __builtin_amdgcn_permlane32_swap(d20, d30, false, false);
    u32x2 r3 = __builtin_amdgcn_permlane32_swap(d21, d31, false, false);
    H8U lo, hi;
    lo.u = (u32x4){r0[0], r1[0], r0[1], r1[1]};
    hi.u = (u32x4){r2[0], r3[0], r2[1], r3[1]};
    f_lo = lo.h;
    f_hi = hi.h;
}

// launch_bounds history:
//   (512,4) -> 64-VGPR cap, ~60 regs spilled, 561 MB scratch writes, 924 us
//   (512,2) -> 128-VGPR cap, still spilling (429 MB writes), AND occupancy
//              showed only 1 WG/CU resident anyway (LDS 2x80KiB didn't fit).
// Live state is ~160-200 VGPRs (f1/f2/f3 frags 80 + acc 16 + temps). LDS
// limits us to 1 WG/CU regardless, so take the full register file: no cap,
// no spills, hoistable loop-invariant biases/W4.
__global__ __launch_bounds__(TPB, 1)
void gnn_mlp(const float* __restrict__ ea,
             const float* __restrict__ W1, const float* __restrict__ b1,
             const float* __restrict__ W2, const float* __restrict__ b2,
             const float* __restrict__ W3, const float* __restrict__ b3,
             const float* __restrict__ W4, const float* __restrict__ b4,
             float* __restrict__ out) {
    __shared__ __align__(16) char LW[LDSB];

    const int tid  = threadIdx.x;
    const int lane = tid & 63;
    const int wv   = tid >> 6;          // wave 0..7
    const int col  = lane & 31;         // edge column of the 32x32 tile
    const int hi   = lane >> 5;         // k-half selector

    // ---- stage weights: f32 -> f16, XOR-swizzled, once per WG ----
    // swizzle: phys = off ^ ((row & 7) << 4)  for 128B rows (w1)
    //          phys = off ^ ((row & 15) << 4) for 256B rows (w2/w3)
    // -> ds_read_b128 of a 32-row column slice lands 2-way per bank (free).
    #pragma unroll
    for (int i = 0; i < 10; ++i) {
        const int g   = i * TPB + tid;  // 16B granule id, 5120 total
        const int off = g << 4;
        const float* src; int phys;
        if (i < 2) {                    // w1: rows of 128 B
            int row = off >> 7;
            phys = W1_OFF + (off ^ ((row & 7) << 4));
            src  = W1 + (off >> 1);
        } else if (i < 6) {             // w2: rows of 256 B
            int rel = off - W2_OFF, row = rel >> 8;
            phys = W2_OFF + (rel ^ ((row & 15) << 4));
            src  = W2 + (rel >> 1);
        } else {                        // w3
            int rel = off - W3_OFF, row = rel >> 8;
            phys = W3_OFF + (rel ^ ((row & 15) << 4));
            src  = W3 + (rel >> 1);
        }
        float4 a = *(const float4*)(src);
        float4 b = *(const float4*)(src + 4);
        half8 h;
        h[0]=(_Float16)a.x; h[1]=(_Float16)a.y; h[2]=(_Float16)a.z; h[3]=(_Float16)a.w;
        h[4]=(_Float16)b.x; h[5]=(_Float16)b.y; h[6]=(_Float16)b.z; h[7]=(_Float16)b.w;
        *(half8*)(LW + phys) = h;
    }
    __syncthreads();   // only barrier in the kernel

    // per-lane swizzled in-row offsets, reused for every tile/layer
    u32 sw2[8], sw1[4];
    #pragma unroll
    for (int s = 0; s < 8; ++s) sw2[s] = (u32)(((s << 5) + (hi << 4)) ^ ((col & 15) << 4));
    #pragma unroll
    for (int s = 0; s < 4; ++s) sw1[s] = (u32)(((s << 5) + (hi << 4)) ^ ((col & 7) << 4));

    const float bb = b4[0];

    for (int blk = blockIdx.x; blk < NBLK; blk += GRID) {
        const long ebase = (long)blk * EPB + wv * EPW;

        // ---- layer-1 B-frags straight from global (f32 -> f16 RNE) ----
        const float* ep = ea + (ebase + col) * IN_F + hi * 8;
        half8 f1[4];
        #pragma unroll
        for (int s = 0; s < 4; ++s) {
            float4 a = *(const float4*)(ep + s * 16);
            float4 b = *(const float4*)(ep + s * 16 + 4);
            half8 h;
            h[0]=(_Float16)a.x; h[1]=(_Float16)a.y; h[2]=(_Float16)a.z; h[3]=(_Float16)a.w;
            h[4]=(_Float16)b.x; h[5]=(_Float16)b.y; h[6]=(_Float16)b.z; h[7]=(_Float16)b.w;
            f1[s] = h;
        }

        // ---- layer 1: 64 -> 128 ----
        half8 f2[8];
        #pragma unroll
        for (int it = 0; it < 4; ++it) {
            f32x16 acc = tile_mm<7, 4>(LW + W1_OFF, sw1, it, col, hi, f1, b1);
            pack_swap(acc, f2[2 * it], f2[2 * it + 1]);
        }

        // ---- layer 2: 128 -> 128 ----
        half8 f3[8];
        #pragma unroll
        for (int it = 0; it < 4; ++it) {
            f32x16 acc = tile_mm<8, 8>(LW + W2_OFF, sw2, it, col, hi, f2, b2);
            pack_swap(acc, f3[2 * it], f3[2 * it + 1]);
        }

        // ---- layer 3 + fused layer-4 dot ----
        float p = 0.0f;
        #pragma unroll
        for (int it = 0; it < 4; ++it) {
            f32x16 acc = tile_mm<8, 8>(LW + W3_OFF, sw2, it, col, hi, f3, b3);
            #pragma unroll
            for (int M = 0; M < 4; ++M) {
                float4 wv4 = *(const float4*)(W4 + it * 32 + M * 8 + hi * 4);
                p += fast_tanh(acc[4*M+0]) * wv4.x + fast_tanh(acc[4*M+1]) * wv4.y
                   + fast_tanh(acc[4*M+2]) * wv4.z + fast_tanh(acc[4*M+3]) * wv4.w;
            }
        }
        // full h-sum for edge `col` lives in lanes col and col+32
        p += __shfl_xor(p, 32, 64);
        if (lane < 32) out[ebase + col] = fast_sigmoid(p + bb);
    }
}

extern "C" void kernel_launch(void* const* d_in, const int* in_sizes, int n_in,
                              void* d_out, int out_size, void* d_ws, size_t ws_size,
                              hipStream_t stream) {
    // setup_inputs order: x, edge_index, edge_attr, W1,b1, W2,b2, W3,b3, W4,b4
    const float* ea = (const float*)d_in[2];
    const float* W1 = (const float*)d_in[3];
    const float* b1 = (const float*)d_in[4];
    const float* W2 = (const float*)d_in[5];
    const float* b2 = (const float*)d_in[6];
    const float* W3 = (const float*)d_in[7];
    const float* b3 = (const float*)d_in[8];
    const float* W4 = (const float*)d_in[9];
    const float* b4 = (const float*)d_in[10];
    float* out = (float*)d_out;

    hipLaunchKernelGGL(gnn_mlp, dim3(GRID), dim3(TPB), 0, stream,
                       ea, W1, b1, W2, b2, W3, b3, W4, b4, out);
}